// Round 1
// baseline (718.603 us; speedup 1.0000x reference)
//
#include <hip/hip_runtime.h>

// Problem constants (VectorQuantizer: inputs [V,N,D] fp32, embeddings [V,D,K] fp32)
#define NV 16
#define NN 8192
#define ND 256
#define NK 1024

typedef __attribute__((ext_vector_type(8))) short short8;
typedef __attribute__((ext_vector_type(4))) float f32x4;

// bf16 helpers (RNE)
__device__ __forceinline__ ushort f2bf(float f) {
    uint32_t u = __float_as_uint(f);
    uint32_t r = (u + 0x7FFFu + ((u >> 16) & 1u)) >> 16;
    return (ushort)r;
}
__device__ __forceinline__ float bf2f(ushort h) {
    return __uint_as_float(((uint32_t)h) << 16);
}

// ---------------------------------------------------------------------------
// Transpose W [V,D,K] -> Wt [V,K,D] fp32 (for gather/wsq) + bf16 limb copies.
// Wlt MUST sit exactly 4194304 ushorts after Wht (score kernel assumes it).
// ---------------------------------------------------------------------------
__global__ void prep_w(const float* __restrict__ W, float* __restrict__ Wt,
                       ushort* __restrict__ Wht, ushort* __restrict__ Wlt) {
    __shared__ float tile[32][33];
    int v = blockIdx.z;
    int k0 = blockIdx.x * 32, d0 = blockIdx.y * 32;
    int tx = threadIdx.x, ty = threadIdx.y;         // block (32,8)
    const float* Wv = W + (size_t)v * ND * NK;
    #pragma unroll
    for (int i = 0; i < 4; ++i)
        tile[ty + 8 * i][tx] = Wv[(size_t)(d0 + ty + 8 * i) * NK + k0 + tx];
    __syncthreads();
    size_t ob = (size_t)v * NK * ND;
    #pragma unroll
    for (int i = 0; i < 4; ++i) {
        float val = tile[tx][ty + 8 * i];
        size_t o = ob + (size_t)(k0 + ty + 8 * i) * ND + d0 + tx;
        Wt[o] = val;
        ushort h = f2bf(val);
        Wht[o] = h;
        Wlt[o] = f2bf(val - bf2f(h));
    }
}

// ---------------------------------------------------------------------------
// wsq from transposed Wt (coalesced): one wave per (v,k) row; double reduce.
// Also zeroes the loss/count accumulators.
// ---------------------------------------------------------------------------
__global__ void wsq_from_wt(const float* __restrict__ Wt, double* __restrict__ wsqd,
                            float* __restrict__ wsqf, double* __restrict__ acc,
                            int* __restrict__ count) {
    int row = blockIdx.x * 4 + (threadIdx.x >> 6);  // V*K rows, 4 waves/block
    int lane = threadIdx.x & 63;
    float4 wv = *(const float4*)(Wt + (size_t)row * ND + lane * 4);
    double s = (double)wv.x * wv.x + (double)wv.y * wv.y +
               (double)wv.z * wv.z + (double)wv.w * wv.w;
    #pragma unroll
    for (int m = 32; m >= 1; m >>= 1) s += __shfl_down(s, m, 64);
    if (lane == 0) { wsqd[row] = s; wsqf[row] = (float)s; }
    if (row == 0 && lane == 0) { *acc = 0.0; *count = 0; }
}

// ---------------------------------------------------------------------------
// X [V,N,D] fp32 -> Xh, Xl bf16 limb arrays (Xl = Xh + 33554432 ushorts).
// ---------------------------------------------------------------------------
__global__ void prep_x(const float* __restrict__ X, ushort* __restrict__ Xh,
                       ushort* __restrict__ Xl) {
    const int nth = gridDim.x * 256;
    for (size_t g = (size_t)blockIdx.x * 256 + threadIdx.x; g < (size_t)NV * NN * ND / 4;
         g += nth) {
        float4 x = *(const float4*)(X + g * 4);
        ushort4 h, l;
        h.x = f2bf(x.x); l.x = f2bf(x.x - bf2f(h.x));
        h.y = f2bf(x.y); l.y = f2bf(x.y - bf2f(h.y));
        h.z = f2bf(x.z); l.z = f2bf(x.z - bf2f(h.z));
        h.w = f2bf(x.w); l.w = f2bf(x.w - bf2f(h.w));
        *(ushort4*)(Xh + g * 4) = h;
        *(ushort4*)(Xl + g * 4) = l;
    }
}

// ---------------------------------------------------------------------------
// MFMA score kernel v4: HK-style 8-phase-family schedule.
//   256 rows x 256 cols per block, 512 threads (8 waves = 4 row x 2 col),
//   double-buffered 128KB LDS (2 x {A 32KB, B 32KB}), XOR-swizzled quads
//   (2-way bank access = free), pre-swizzled global source + linear
//   global_load_lds dest, counted-drain pipeline: stage step t+1 during the
//   MFMA phases of step t, single vmcnt(0) per step (never per phase),
//   raw s_barrier + explicit lgkmcnt(0) + setprio(1) around MFMA clusters.
// 2-limb bf16: dot = Xh.Wh + Xh.Wl + Xl.Wh. Tracks best + second-best.
// XCD-aware block->v mapping (each XCD sees 2 codebooks -> B fits its L2).
// ---------------------------------------------------------------------------
#define GLOAD16(SRC, DST)                                                     \
    __builtin_amdgcn_global_load_lds(                                         \
        (const __attribute__((address_space(1))) void*)(SRC),                 \
        (__attribute__((address_space(3))) void*)(DST), 16, 0, 0)

__global__ __launch_bounds__(512, 2) void score_mfma(
    const ushort* __restrict__ Xh, const ushort* __restrict__ Wht,
    const float* __restrict__ wsqf, int* __restrict__ idx, float* __restrict__ marg) {
    // Per buffer (64KB): A [0,32768): limb stride 16384B, slot u16-quad = r*4 + (q ^ ((r>>1)&3))
    //                    B [32768,65536): limb stride 16384B, slot = c*4 + (q ^ ((c>>1)&3))
    // Buffer 1 at +65536.
    __shared__ __align__(16) unsigned char smem[131072];

    const int tid = threadIdx.x;
    const int w = tid >> 6;
    const int l15 = tid & 15;
    const int l4 = (tid >> 4) & 3;
    const int wr = w & 3;                            // row group (64 rows each)
    const int wc = w >> 2;                           // col group (128 cols each)
    const int b = blockIdx.x;
    const int v = (b & 7) * 2 + ((b >> 3) & 1);      // XCD swizzle: 2 codebooks/XCD
    const int n0 = (b >> 4) * 256;

    const ushort* Abase = Xh + (size_t)(v * NN + n0) * ND;     // lo limb at +33554432
    const ushort* Bbase = Wht + (size_t)v * NK * ND;           // lo limb at +4194304

    // staging source offsets (u16 units), constant per thread; A and B share
    // the same (limb, row/col, quad) decomposition: 2048 segs of 16B each.
    unsigned aoff[4], boff[4];
    #pragma unroll
    for (int i = 0; i < 4; ++i) {
        int seg = i * 512 + tid;
        int L = seg >> 10, r = (seg >> 2) & 255, qs = seg & 3;
        int q = qs ^ ((r >> 1) & 3);                 // swizzle: slot qs holds quad q
        aoff[i] = (unsigned)L * 33554432u + (unsigned)r * 256u + (unsigned)q * 8u;
        boff[i] = (unsigned)L * 4194304u + (unsigned)r * 256u + (unsigned)q * 8u;
    }
    // fragment read offsets (bytes within a buffer), constant per thread
    unsigned aro[4], bco[8];
    #pragma unroll
    for (int rt = 0; rt < 4; ++rt) {
        int row = wr * 64 + rt * 16 + l15;
        aro[rt] = (unsigned)(row * 4 + (l4 ^ ((row >> 1) & 3))) * 16u;
    }
    #pragma unroll
    for (int ct = 0; ct < 8; ++ct) {
        int col = wc * 128 + ct * 16 + l15;
        bco[ct] = 32768u + (unsigned)(col * 4 + (l4 ^ ((col >> 1) & 3))) * 16u;
    }

    float m1[16], m2[16];
    int c1[16];
    #pragma unroll
    for (int s = 0; s < 16; ++s) { m1[s] = 3.0e38f; m2[s] = 3.0e38f; c1[s] = 0; }

    f32x4 acc[4][8];
    #pragma unroll
    for (int i = 0; i < 4; ++i)
        #pragma unroll
        for (int j = 0; j < 8; ++j) acc[i][j] = (f32x4){0.f, 0.f, 0.f, 0.f};

    // prologue: stage step 0 into buffer 0, full drain once
    #pragma unroll
    for (int i = 0; i < 4; ++i)
        GLOAD16(Abase + aoff[i], smem + (unsigned)(i * 512 + tid) * 16u);
    #pragma unroll
    for (int i = 0; i < 4; ++i)
        GLOAD16(Bbase + boff[i], smem + 32768u + (unsigned)(i * 512 + tid) * 16u);
    __syncthreads();

    // 32 K-steps: cc = t>>3 (256-col chunk), dc = t&7 (32-d slice)
    #pragma unroll 1
    for (int t = 0; t < 32; ++t) {
        const unsigned pb = (t & 1) ? 65536u : 0u;   // compute buffer
        const unsigned nb = pb ^ 65536u;             // staging buffer
        const int tn = t + 1;
        const unsigned d0n = (unsigned)(tn & 7) * 32u;
        const unsigned ccn = (unsigned)(tn >> 3) * 65536u;   // (cc*256 cols)*ND u16
        short8 Ah[4], Al[4];

        #pragma unroll
        for (int ph = 0; ph < 4; ++ph) {
            // ds-load register subtiles for this phase's ct pair
            short8 Bh0 = *(const short8*)(smem + pb + bco[2 * ph]);
            short8 Bl0 = *(const short8*)(smem + pb + bco[2 * ph] + 16384u);
            short8 Bh1 = *(const short8*)(smem + pb + bco[2 * ph + 1]);
            short8 Bl1 = *(const short8*)(smem + pb + bco[2 * ph + 1] + 16384u);
            if (ph == 0) {
                #pragma unroll
                for (int rt = 0; rt < 4; ++rt) {
                    Ah[rt] = *(const short8*)(smem + pb + aro[rt]);
                    Al[rt] = *(const short8*)(smem + pb + aro[rt] + 16384u);
                }
                if (t < 31) {                        // issue next-step A stage
                    #pragma unroll
                    for (int i = 0; i < 4; ++i)
                        GLOAD16(Abase + aoff[i] + d0n,
                                smem + nb + (unsigned)(i * 512 + tid) * 16u);
                }
            }
            if (ph == 1 && t < 31) {                 // issue next-step B stage
                #pragma unroll
                for (int i = 0; i < 4; ++i)
                    GLOAD16(Bbase + ccn + boff[i] + d0n,
                            smem + nb + 32768u + (unsigned)(i * 512 + tid) * 16u);
            }
            __builtin_amdgcn_s_barrier();
            asm volatile("s_waitcnt lgkmcnt(0)" ::: "memory");
            __builtin_amdgcn_sched_barrier(0);
            __builtin_amdgcn_s_setprio(1);
            #pragma unroll
            for (int rt = 0; rt < 4; ++rt) {
                f32x4 a0 = acc[rt][2 * ph];
                a0 = __builtin_amdgcn_mfma_f32_16x16x32_bf16(Ah[rt], Bh0, a0, 0, 0, 0);
                a0 = __builtin_amdgcn_mfma_f32_16x16x32_bf16(Ah[rt], Bl0, a0, 0, 0, 0);
                a0 = __builtin_amdgcn_mfma_f32_16x16x32_bf16(Al[rt], Bh0, a0, 0, 0, 0);
                acc[rt][2 * ph] = a0;
                f32x4 a1 = acc[rt][2 * ph + 1];
                a1 = __builtin_amdgcn_mfma_f32_16x16x32_bf16(Ah[rt], Bh1, a1, 0, 0, 0);
                a1 = __builtin_amdgcn_mfma_f32_16x16x32_bf16(Ah[rt], Bl1, a1, 0, 0, 0);
                a1 = __builtin_amdgcn_mfma_f32_16x16x32_bf16(Al[rt], Bh1, a1, 0, 0, 0);
                acc[rt][2 * ph + 1] = a1;
            }
            __builtin_amdgcn_s_setprio(0);
            __builtin_amdgcn_sched_barrier(0);
            if (ph == 3)                             // one drain per step, not per phase
                asm volatile("s_waitcnt vmcnt(0)" ::: "memory");
            __builtin_amdgcn_s_barrier();
        }

        if ((t & 7) == 7) {
            // fold chunk scores into running best/second (lane stream ascending c)
            const int ccc = t >> 3;
            #pragma unroll
            for (int ct = 0; ct < 8; ++ct) {
                int c = ccc * 256 + wc * 128 + ct * 16 + l15;
                float wf = wsqf[v * NK + c];
                #pragma unroll
                for (int rt = 0; rt < 4; ++rt)
                    #pragma unroll
                    for (int reg = 0; reg < 4; ++reg) {
                        int slot = rt * 4 + reg;
                        float s = fmaf(-2.0f, acc[rt][ct][reg], wf);
                        bool better = s < m1[slot];
                        m2[slot] = better ? m1[slot] : fminf(m2[slot], s);
                        c1[slot] = better ? c : c1[slot];
                        m1[slot] = better ? s : m1[slot];
                    }
            }
            #pragma unroll
            for (int i = 0; i < 4; ++i)
                #pragma unroll
                for (int j = 0; j < 8; ++j) acc[i][j] = (f32x4){0.f, 0.f, 0.f, 0.f};
        }
    }
    __syncthreads();

    // merge across the 16 lanes sharing each row (C layout: col = lane&15)
    float* mS = (float*)smem;                        // [2][256]
    int* mC = (int*)(smem + 2048);
    float* mS2 = (float*)(smem + 4096);
    #pragma unroll
    for (int rt = 0; rt < 4; ++rt)
        #pragma unroll
        for (int reg = 0; reg < 4; ++reg) {
            int slot = rt * 4 + reg;
            float s1 = m1[slot], s2v = m2[slot];
            int c = c1[slot];
            #pragma unroll
            for (int m = 1; m < 16; m <<= 1) {
                float s1o = __shfl_xor(s1, m, 64);
                float s2o = __shfl_xor(s2v, m, 64);
                int co = __shfl_xor(c, m, 64);
                bool take = (s1o < s1) || (s1o == s1 && co < c);  // tie -> smaller c
                float big = take ? s1 : s1o;
                s2v = fminf(fminf(s2v, s2o), big);
                s1 = take ? s1o : s1;
                c = take ? co : c;
            }
            if (l15 == 0) {
                int rowl = wr * 64 + rt * 16 + l4 * 4 + reg;  // C row = quad*4+reg
                mS[wc * 256 + rowl] = s1;
                mC[wc * 256 + rowl] = c;
                mS2[wc * 256 + rowl] = s2v;
            }
        }
    __syncthreads();
    if (tid < 256) {                                  // merge the two col-halves
        float s1a = mS[tid], s1b = mS[256 + tid];
        int ca = mC[tid], cb = mC[256 + tid];
        float s2a = mS2[tid], s2b = mS2[256 + tid];
        bool take = (s1b < s1a) || (s1b == s1a && cb < ca);
        float s1 = take ? s1b : s1a;
        int c = take ? cb : ca;
        float s2v = fminf(fminf(s2a, s2b), take ? s1a : s1b);
        idx[v * NN + n0 + tid] = c;
        marg[v * NN + n0 + tid] = s2v - s1;
    }
}
#undef GLOAD16

// Rows with small margin -> compacted list for exact rescoring.
__global__ void compact(const float* __restrict__ marg, int* __restrict__ list,
                        int* __restrict__ count) {
    int r = blockIdx.x * 256 + threadIdx.x;
    if (marg[r] < 0.04f) {
        int p = atomicAdd(count, 1);
        list[p] = r;
    }
}

// Exact fp32 rescore (sequential fmaf over d, double compare, tie -> smaller c)
__global__ __launch_bounds__(256) void rescore(
    const float* __restrict__ X, const float* __restrict__ W,
    const double* __restrict__ wsqd, const int* __restrict__ list,
    const int* __restrict__ count, int* __restrict__ idx) {
    __shared__ float xs[256];
    __shared__ double rs[4];
    __shared__ int rc[4];
    int tid = threadIdx.x;
    int nrows = *count;
    for (int j = blockIdx.x; j < nrows; j += gridDim.x) {
        int row = list[j];
        int v = row >> 13;
        __syncthreads();
        xs[tid] = X[(size_t)row * ND + tid];
        __syncthreads();
        const float* Wv = W + (size_t)v * ND * NK;
        float p0 = 0.f, p1 = 0.f, p2 = 0.f, p3 = 0.f;
        int cb = tid * 4;
        for (int d = 0; d < ND; ++d) {
            float xd = xs[d];
            float4 wv = *(const float4*)(Wv + (size_t)d * NK + cb);
            p0 = fmaf(xd, wv.x, p0);
            p1 = fmaf(xd, wv.y, p1);
            p2 = fmaf(xd, wv.z, p2);
            p3 = fmaf(xd, wv.w, p3);
        }
        const double* wv2 = wsqd + v * NK;
        double s0 = wv2[cb] - 2.0 * (double)p0;
        double s1 = wv2[cb + 1] - 2.0 * (double)p1;
        double s2 = wv2[cb + 2] - 2.0 * (double)p2;
        double s3 = wv2[cb + 3] - 2.0 * (double)p3;
        double bsv = s0;
        int bcv = cb;
        if (s1 < bsv) { bsv = s1; bcv = cb + 1; }
        if (s2 < bsv) { bsv = s2; bcv = cb + 2; }
        if (s3 < bsv) { bsv = s3; bcv = cb + 3; }
        for (int m = 1; m < 64; m <<= 1) {
            double so = __shfl_xor(bsv, m, 64);
            int co = __shfl_xor(bcv, m, 64);
            if (so < bsv || (so == bsv && co < bcv)) { bsv = so; bcv = co; }
        }
        if ((tid & 63) == 0) { rs[tid >> 6] = bsv; rc[tid >> 6] = bcv; }
        __syncthreads();
        if (tid == 0) {
            double bq = rs[0];
            int c = rc[0];
            for (int i2 = 1; i2 < 4; ++i2)
                if (rs[i2] < bq || (rs[i2] == bq && rc[i2] < c)) { bq = rs[i2]; c = rc[i2]; }
            idx[row] = c;
        }
        __syncthreads();
    }
}

// Gather quantized rows, write output = x + (q - x), accumulate sum (q-x)^2.
__global__ void gather_loss(const float* __restrict__ X, const float* __restrict__ Wt,
                            const int* __restrict__ idx, float* __restrict__ out,
                            double* __restrict__ acc) {
    int tid = threadIdx.x;
    float lsum = 0.f;
    #pragma unroll
    for (int i = 0; i < 2; ++i) {
        int flat = i * 256 + tid;
        int rl = flat >> 6;
        int dpos = (flat & 63) * 4;
        size_t row = (size_t)blockIdx.x * 8 + rl;
        int k = idx[row];
        int v = (int)(row >> 13);
        float4 q = *(const float4*)(Wt + ((size_t)v * NK + k) * ND + dpos);
        float4 x = *(const float4*)(X + row * ND + dpos);
        float dx0 = q.x - x.x, dx1 = q.y - x.y, dx2 = q.z - x.z, dx3 = q.w - x.w;
        float4 o;
        o.x = x.x + dx0; o.y = x.y + dx1; o.z = x.z + dx2; o.w = x.w + dx3;
        *(float4*)(out + row * ND + dpos) = o;
        lsum += dx0 * dx0 + dx1 * dx1 + dx2 * dx2 + dx3 * dx3;
    }
    #pragma unroll
    for (int m = 32; m >= 1; m >>= 1) lsum += __shfl_down(lsum, m, 64);
    __shared__ float ws4[4];
    if ((tid & 63) == 0) ws4[tid >> 6] = lsum;
    __syncthreads();
    if (tid == 0) {
        float tot = ws4[0] + ws4[1] + ws4[2] + ws4[3];
        atomicAdd(acc, (double)tot);
    }
}

__global__ void finalize_loss(const double* __restrict__ acc, float* __restrict__ outLoss) {
    *outLoss = (float)(1.25 * (*acc) / (double)((size_t)NV * NN * ND));
}

// ===========================================================================
extern "C" void kernel_launch(void* const* d_in, const int* in_sizes, int n_in,
                              void* d_out, int out_size, void* d_ws, size_t ws_size,
                              hipStream_t stream) {
    const float* X = (const float*)d_in[0];   // [16, 8192, 256]
    const float* W = (const float*)d_in[1];   // [16, 256, 1024]
    float* out = (float*)d_out;               // [16,8192,256] + loss scalar
    char* ws = (char*)d_ws;

    // Workspace layout (Xl contiguous after Xh; Wlt contiguous after Wht)
    const size_t oXh = 0;
    const size_t oXl = oXh + 67108864;
    const size_t oWht = oXl + 67108864;       // 134217728
    const size_t oWlt = oWht + 8388608;       // 142606336
    const size_t oWt = oWlt + 8388608;        // 150994944
    const size_t oWsqd = oWt + 16777216;      // 167772160
    const size_t oWsqf = oWsqd + 131072;      // 167903232
    const size_t oIdx = oWsqf + 65536;        // 167968768
    const size_t oMarg = oIdx + 524288;       // 168493056
    const size_t oList = oMarg + 524288;      // 169017344
    const size_t oAcc = oList + 524288;       // 169541632
    const size_t oCount = oAcc + 8;

    ushort* Xh = (ushort*)(ws + oXh);
    ushort* Xl = (ushort*)(ws + oXl);
    ushort* Wht = (ushort*)(ws + oWht);
    ushort* Wlt = (ushort*)(ws + oWlt);
    float* Wt = (float*)(ws + oWt);
    double* wsqd = (double*)(ws + oWsqd);
    float* wsqf = (float*)(ws + oWsqf);
    int* idx = (int*)(ws + oIdx);
    float* marg = (float*)(ws + oMarg);
    int* list = (int*)(ws + oList);
    double* acc = (double*)(ws + oAcc);
    int* count = (int*)(ws + oCount);

    prep_w<<<dim3(NK / 32, ND / 32, NV), dim3(32, 8), 0, stream>>>(W, Wt, Wht, Wlt);
    wsq_from_wt<<<NV * NK / 4, 256, 0, stream>>>(Wt, wsqd, wsqf, acc, count);
    prep_x<<<2048, 256, 0, stream>>>(X, Xh, Xl);
    score_mfma<<<(NV * NN) / 256, 512, 0, stream>>>(Xh, Wht, wsqf, idx, marg);
    compact<<<(NV * NN) / 256, 256, 0, stream>>>(marg, list, count);
    rescore<<<256, 256, 0, stream>>>(X, W, wsqd, list, count, idx);
    gather_loss<<<(NV * NN) / 8, 256, 0, stream>>>(X, Wt, idx, out, acc);
    finalize_loss<<<1, 1, 0, stream>>>(acc, out + (size_t)NV * NN * ND);
}

// Round 2
// 705.013 us; speedup vs baseline: 1.0193x; 1.0193x over previous
//
#include <hip/hip_runtime.h>

// Problem constants (VectorQuantizer: inputs [V,N,D] fp32, embeddings [V,D,K] fp32)
#define NV 16
#define NN 8192
#define ND 256
#define NK 1024

typedef __attribute__((ext_vector_type(8))) short short8;
typedef __attribute__((ext_vector_type(4))) float f32x4;

// bf16 helpers (RNE)
__device__ __forceinline__ ushort f2bf(float f) {
    uint32_t u = __float_as_uint(f);
    uint32_t r = (u + 0x7FFFu + ((u >> 16) & 1u)) >> 16;
    return (ushort)r;
}
__device__ __forceinline__ float bf2f(ushort h) {
    return __uint_as_float(((uint32_t)h) << 16);
}

// ---------------------------------------------------------------------------
// Transpose W [V,D,K] -> Wt [V,K,D] fp32 (for gather/wsq) + bf16 limb copies.
// Wlt MUST sit exactly 4194304 ushorts after Wht (score kernel assumes it).
// ---------------------------------------------------------------------------
__global__ void prep_w(const float* __restrict__ W, float* __restrict__ Wt,
                       ushort* __restrict__ Wht, ushort* __restrict__ Wlt) {
    __shared__ float tile[32][33];
    int v = blockIdx.z;
    int k0 = blockIdx.x * 32, d0 = blockIdx.y * 32;
    int tx = threadIdx.x, ty = threadIdx.y;         // block (32,8)
    const float* Wv = W + (size_t)v * ND * NK;
    #pragma unroll
    for (int i = 0; i < 4; ++i)
        tile[ty + 8 * i][tx] = Wv[(size_t)(d0 + ty + 8 * i) * NK + k0 + tx];
    __syncthreads();
    size_t ob = (size_t)v * NK * ND;
    #pragma unroll
    for (int i = 0; i < 4; ++i) {
        float val = tile[tx][ty + 8 * i];
        size_t o = ob + (size_t)(k0 + ty + 8 * i) * ND + d0 + tx;
        Wt[o] = val;
        ushort h = f2bf(val);
        Wht[o] = h;
        Wlt[o] = f2bf(val - bf2f(h));
    }
}

// ---------------------------------------------------------------------------
// wsq from transposed Wt (coalesced): one wave per (v,k) row; double reduce.
// Also zeroes the loss/count accumulators.
// ---------------------------------------------------------------------------
__global__ void wsq_from_wt(const float* __restrict__ Wt, double* __restrict__ wsqd,
                            float* __restrict__ wsqf, double* __restrict__ acc,
                            int* __restrict__ count) {
    int row = blockIdx.x * 4 + (threadIdx.x >> 6);  // V*K rows, 4 waves/block
    int lane = threadIdx.x & 63;
    float4 wv = *(const float4*)(Wt + (size_t)row * ND + lane * 4);
    double s = (double)wv.x * wv.x + (double)wv.y * wv.y +
               (double)wv.z * wv.z + (double)wv.w * wv.w;
    #pragma unroll
    for (int m = 32; m >= 1; m >>= 1) s += __shfl_down(s, m, 64);
    if (lane == 0) { wsqd[row] = s; wsqf[row] = (float)s; }
    if (row == 0 && lane == 0) { *acc = 0.0; *count = 0; }
}

// ---------------------------------------------------------------------------
// X [V,N,D] fp32 -> Xh, Xl bf16 limb arrays (Xl = Xh + 33554432 ushorts).
// ---------------------------------------------------------------------------
__global__ void prep_x(const float* __restrict__ X, ushort* __restrict__ Xh,
                       ushort* __restrict__ Xl) {
    const int nth = gridDim.x * 256;
    for (size_t g = (size_t)blockIdx.x * 256 + threadIdx.x; g < (size_t)NV * NN * ND / 4;
         g += nth) {
        float4 x = *(const float4*)(X + g * 4);
        ushort4 h, l;
        h.x = f2bf(x.x); l.x = f2bf(x.x - bf2f(h.x));
        h.y = f2bf(x.y); l.y = f2bf(x.y - bf2f(h.y));
        h.z = f2bf(x.z); l.z = f2bf(x.z - bf2f(h.z));
        h.w = f2bf(x.w); l.w = f2bf(x.w - bf2f(h.w));
        *(ushort4*)(Xh + g * 4) = h;
        *(ushort4*)(Xl + g * 4) = l;
    }
}

// ---------------------------------------------------------------------------
// MFMA score kernel v5: barrier-minimal double-buffered pipeline.
//   Diagnosis (r0/r1 both 219us, MfmaUtil ~40%): per-phase barriers +
//   lgkmcnt(0) lockstep serialize the LDS-read pipe against the matrix pipe
//   (reads 2304cyc + MFMA 3725cyc + DMA 512cyc + 8x barrier ~= observed
//   8212cyc/step). Fix: ONE __syncthreads per K-step (it both drains this
//   wave's staging vmcnt for the buffer about to be read - issued a full
//   step earlier, ~6000cyc cover vs ~1700cyc service - and licenses
//   overwriting the other buffer). Inside a step: no barriers, no manual
//   waitcnt; B-fragment reads software-pipelined one phase ahead so the
//   compiler emits counted lgkmcnt and the 2 waves/SIMD desync to overlap
//   LDS reads with MFMAs (m114 mechanism).
//   256 rows x 256 cols per block, 512 threads (8 waves = 4 row x 2 col),
//   2 x 64KB LDS buffers, XOR-swizzled quads, pre-swizzled global source +
//   linear global_load_lds dest. 2-limb bf16: dot = Xh.Wh + Xh.Wl + Xl.Wh.
//   Tracks best + second-best. XCD-aware block->v mapping.
// ---------------------------------------------------------------------------
#define GLOAD16(SRC, DST)                                                     \
    __builtin_amdgcn_global_load_lds(                                         \
        (const __attribute__((address_space(1))) void*)(SRC),                 \
        (__attribute__((address_space(3))) void*)(DST), 16, 0, 0)

__global__ __launch_bounds__(512, 2) void score_mfma(
    const ushort* __restrict__ Xh, const ushort* __restrict__ Wht,
    const float* __restrict__ wsqf, int* __restrict__ idx, float* __restrict__ marg) {
    // Per buffer (64KB): A [0,32768): limb stride 16384B, slot u16-quad = r*4 + (q ^ ((r>>1)&3))
    //                    B [32768,65536): limb stride 16384B, slot = c*4 + (q ^ ((c>>1)&3))
    // Buffer 1 at +65536.
    __shared__ __align__(16) unsigned char smem[131072];

    const int tid = threadIdx.x;
    const int w = tid >> 6;
    const int l15 = tid & 15;
    const int l4 = (tid >> 4) & 3;
    const int wr = w & 3;                            // row group (64 rows each)
    const int wc = w >> 2;                           // col group (128 cols each)
    const int b = blockIdx.x;
    const int v = (b & 7) * 2 + ((b >> 3) & 1);      // XCD swizzle: 2 codebooks/XCD
    const int n0 = (b >> 4) * 256;

    const ushort* Abase = Xh + (size_t)(v * NN + n0) * ND;     // lo limb at +33554432
    const ushort* Bbase = Wht + (size_t)v * NK * ND;           // lo limb at +4194304

    // staging source offsets (u16 units), constant per thread; A and B share
    // the same (limb, row/col, quad) decomposition: 2048 segs of 16B each.
    unsigned aoff[4], boff[4];
    #pragma unroll
    for (int i = 0; i < 4; ++i) {
        int seg = i * 512 + tid;
        int L = seg >> 10, r = (seg >> 2) & 255, qs = seg & 3;
        int q = qs ^ ((r >> 1) & 3);                 // swizzle: slot qs holds quad q
        aoff[i] = (unsigned)L * 33554432u + (unsigned)r * 256u + (unsigned)q * 8u;
        boff[i] = (unsigned)L * 4194304u + (unsigned)r * 256u + (unsigned)q * 8u;
    }
    // fragment read offsets (bytes within a buffer), constant per thread
    unsigned aro[4], bco[8];
    #pragma unroll
    for (int rt = 0; rt < 4; ++rt) {
        int row = wr * 64 + rt * 16 + l15;
        aro[rt] = (unsigned)(row * 4 + (l4 ^ ((row >> 1) & 3))) * 16u;
    }
    #pragma unroll
    for (int ct = 0; ct < 8; ++ct) {
        int col = wc * 128 + ct * 16 + l15;
        bco[ct] = 32768u + (unsigned)(col * 4 + (l4 ^ ((col >> 1) & 3))) * 16u;
    }

    float m1[16], m2[16];
    int c1[16];
    #pragma unroll
    for (int s = 0; s < 16; ++s) { m1[s] = 3.0e38f; m2[s] = 3.0e38f; c1[s] = 0; }

    f32x4 acc[4][8];
    #pragma unroll
    for (int i = 0; i < 4; ++i)
        #pragma unroll
        for (int j = 0; j < 8; ++j) acc[i][j] = (f32x4){0.f, 0.f, 0.f, 0.f};

    // prologue: stage step 0 into buffer 0 (drained by first __syncthreads)
    #pragma unroll
    for (int i = 0; i < 4; ++i)
        GLOAD16(Abase + aoff[i], smem + (unsigned)(i * 512 + tid) * 16u);
    #pragma unroll
    for (int i = 0; i < 4; ++i)
        GLOAD16(Bbase + boff[i], smem + 32768u + (unsigned)(i * 512 + tid) * 16u);

    // 32 K-steps: cc (256-col chunk) x dc (32-d slice)
    #pragma unroll 1
    for (int cc = 0; cc < 4; ++cc) {
        #pragma unroll 1
        for (int dc = 0; dc < 8; ++dc) {
            const int t = cc * 8 + dc;
            const unsigned pb = (t & 1) ? 65536u : 0u;   // compute buffer
            const unsigned nb = pb ^ 65536u;             // staging buffer

            // ONE barrier per step: drains own staging vmcnt (buffer pb now
            // valid) + all waves done reading nb last step (safe to overwrite)
            __syncthreads();

            if (t < 31) {                            // issue next-step stage ASAP
                const int tn = t + 1;
                const unsigned d0n = (unsigned)(tn & 7) * 32u;
                const unsigned ccn = (unsigned)(tn >> 3) * 65536u;
                #pragma unroll
                for (int i = 0; i < 4; ++i)
                    GLOAD16(Abase + aoff[i] + d0n,
                            smem + nb + (unsigned)(i * 512 + tid) * 16u);
                #pragma unroll
                for (int i = 0; i < 4; ++i)
                    GLOAD16(Bbase + ccn + boff[i] + d0n,
                            smem + nb + 32768u + (unsigned)(i * 512 + tid) * 16u);
            }

            // A fragments for the step
            short8 Ah[4], Al[4];
            #pragma unroll
            for (int rt = 0; rt < 4; ++rt) {
                Ah[rt] = *(const short8*)(smem + pb + aro[rt]);
                Al[rt] = *(const short8*)(smem + pb + aro[rt] + 16384u);
            }
            // B fragments: software-pipelined one phase ahead ([ph&1] slots,
            // ph is compile-time under unroll -> static indexing)
            short8 Bh[2][2], Bl[2][2];
            Bh[0][0] = *(const short8*)(smem + pb + bco[0]);
            Bl[0][0] = *(const short8*)(smem + pb + bco[0] + 16384u);
            Bh[0][1] = *(const short8*)(smem + pb + bco[1]);
            Bl[0][1] = *(const short8*)(smem + pb + bco[1] + 16384u);
            #pragma unroll
            for (int ph = 0; ph < 4; ++ph) {
                const int cur = ph & 1, nxt = cur ^ 1;
                if (ph < 3) {                        // prefetch next phase's B
                    Bh[nxt][0] = *(const short8*)(smem + pb + bco[2 * ph + 2]);
                    Bl[nxt][0] = *(const short8*)(smem + pb + bco[2 * ph + 2] + 16384u);
                    Bh[nxt][1] = *(const short8*)(smem + pb + bco[2 * ph + 3]);
                    Bl[nxt][1] = *(const short8*)(smem + pb + bco[2 * ph + 3] + 16384u);
                }
                __builtin_amdgcn_s_setprio(1);
                #pragma unroll
                for (int rt = 0; rt < 4; ++rt) {
                    f32x4 a0 = acc[rt][2 * ph];
                    a0 = __builtin_amdgcn_mfma_f32_16x16x32_bf16(Ah[rt], Bh[cur][0], a0, 0, 0, 0);
                    a0 = __builtin_amdgcn_mfma_f32_16x16x32_bf16(Ah[rt], Bl[cur][0], a0, 0, 0, 0);
                    a0 = __builtin_amdgcn_mfma_f32_16x16x32_bf16(Al[rt], Bh[cur][0], a0, 0, 0, 0);
                    acc[rt][2 * ph] = a0;
                    f32x4 a1 = acc[rt][2 * ph + 1];
                    a1 = __builtin_amdgcn_mfma_f32_16x16x32_bf16(Ah[rt], Bh[cur][1], a1, 0, 0, 0);
                    a1 = __builtin_amdgcn_mfma_f32_16x16x32_bf16(Ah[rt], Bl[cur][1], a1, 0, 0, 0);
                    a1 = __builtin_amdgcn_mfma_f32_16x16x32_bf16(Al[rt], Bh[cur][1], a1, 0, 0, 0);
                    acc[rt][2 * ph + 1] = a1;
                }
                __builtin_amdgcn_s_setprio(0);
            }
        }
        // fold chunk scores into running best/second (lane stream ascending c)
        #pragma unroll
        for (int ct = 0; ct < 8; ++ct) {
            int c = cc * 256 + wc * 128 + ct * 16 + l15;
            float wf = wsqf[v * NK + c];
            #pragma unroll
            for (int rt = 0; rt < 4; ++rt)
                #pragma unroll
                for (int reg = 0; reg < 4; ++reg) {
                    int slot = rt * 4 + reg;
                    float s = fmaf(-2.0f, acc[rt][ct][reg], wf);
                    bool better = s < m1[slot];
                    m2[slot] = better ? m1[slot] : fminf(m2[slot], s);
                    c1[slot] = better ? c : c1[slot];
                    m1[slot] = better ? s : m1[slot];
                }
        }
        #pragma unroll
        for (int i = 0; i < 4; ++i)
            #pragma unroll
            for (int j = 0; j < 8; ++j) acc[i][j] = (f32x4){0.f, 0.f, 0.f, 0.f};
    }
    __syncthreads();

    // merge across the 16 lanes sharing each row (C layout: col = lane&15)
    float* mS = (float*)smem;                        // [2][256]
    int* mC = (int*)(smem + 2048);
    float* mS2 = (float*)(smem + 4096);
    #pragma unroll
    for (int rt = 0; rt < 4; ++rt)
        #pragma unroll
        for (int reg = 0; reg < 4; ++reg) {
            int slot = rt * 4 + reg;
            float s1 = m1[slot], s2v = m2[slot];
            int c = c1[slot];
            #pragma unroll
            for (int m = 1; m < 16; m <<= 1) {
                float s1o = __shfl_xor(s1, m, 64);
                float s2o = __shfl_xor(s2v, m, 64);
                int co = __shfl_xor(c, m, 64);
                bool take = (s1o < s1) || (s1o == s1 && co < c);  // tie -> smaller c
                float big = take ? s1 : s1o;
                s2v = fminf(fminf(s2v, s2o), big);
                s1 = take ? s1o : s1;
                c = take ? co : c;
            }
            if (l15 == 0) {
                int rowl = wr * 64 + rt * 16 + l4 * 4 + reg;  // C row = quad*4+reg
                mS[wc * 256 + rowl] = s1;
                mC[wc * 256 + rowl] = c;
                mS2[wc * 256 + rowl] = s2v;
            }
        }
    __syncthreads();
    if (tid < 256) {                                  // merge the two col-halves
        float s1a = mS[tid], s1b = mS[256 + tid];
        int ca = mC[tid], cb = mC[256 + tid];
        float s2a = mS2[tid], s2b = mS2[256 + tid];
        bool take = (s1b < s1a) || (s1b == s1a && cb < ca);
        float s1 = take ? s1b : s1a;
        int c = take ? cb : ca;
        float s2v = fminf(fminf(s2a, s2b), take ? s1a : s1b);
        idx[v * NN + n0 + tid] = c;
        marg[v * NN + n0 + tid] = s2v - s1;
    }
}
#undef GLOAD16

// Rows with small margin -> compacted list for exact rescoring.
__global__ void compact(const float* __restrict__ marg, int* __restrict__ list,
                        int* __restrict__ count) {
    int r = blockIdx.x * 256 + threadIdx.x;
    if (marg[r] < 0.04f) {
        int p = atomicAdd(count, 1);
        list[p] = r;
    }
}

// Exact fp32 rescore (sequential fmaf over d, double compare, tie -> smaller c)
__global__ __launch_bounds__(256) void rescore(
    const float* __restrict__ X, const float* __restrict__ W,
    const double* __restrict__ wsqd, const int* __restrict__ list,
    const int* __restrict__ count, int* __restrict__ idx) {
    __shared__ float xs[256];
    __shared__ double rs[4];
    __shared__ int rc[4];
    int tid = threadIdx.x;
    int nrows = *count;
    for (int j = blockIdx.x; j < nrows; j += gridDim.x) {
        int row = list[j];
        int v = row >> 13;
        __syncthreads();
        xs[tid] = X[(size_t)row * ND + tid];
        __syncthreads();
        const float* Wv = W + (size_t)v * ND * NK;
        float p0 = 0.f, p1 = 0.f, p2 = 0.f, p3 = 0.f;
        int cb = tid * 4;
        for (int d = 0; d < ND; ++d) {
            float xd = xs[d];
            float4 wv = *(const float4*)(Wv + (size_t)d * NK + cb);
            p0 = fmaf(xd, wv.x, p0);
            p1 = fmaf(xd, wv.y, p1);
            p2 = fmaf(xd, wv.z, p2);
            p3 = fmaf(xd, wv.w, p3);
        }
        const double* wv2 = wsqd + v * NK;
        double s0 = wv2[cb] - 2.0 * (double)p0;
        double s1 = wv2[cb + 1] - 2.0 * (double)p1;
        double s2 = wv2[cb + 2] - 2.0 * (double)p2;
        double s3 = wv2[cb + 3] - 2.0 * (double)p3;
        double bsv = s0;
        int bcv = cb;
        if (s1 < bsv) { bsv = s1; bcv = cb + 1; }
        if (s2 < bsv) { bsv = s2; bcv = cb + 2; }
        if (s3 < bsv) { bsv = s3; bcv = cb + 3; }
        for (int m = 1; m < 64; m <<= 1) {
            double so = __shfl_xor(bsv, m, 64);
            int co = __shfl_xor(bcv, m, 64);
            if (so < bsv || (so == bsv && co < bcv)) { bsv = so; bcv = co; }
        }
        if ((tid & 63) == 0) { rs[tid >> 6] = bsv; rc[tid >> 6] = bcv; }
        __syncthreads();
        if (tid == 0) {
            double bq = rs[0];
            int c = rc[0];
            for (int i2 = 1; i2 < 4; ++i2)
                if (rs[i2] < bq || (rs[i2] == bq && rc[i2] < c)) { bq = rs[i2]; c = rc[i2]; }
            idx[row] = c;
        }
        __syncthreads();
    }
}

// Gather quantized rows, write output = x + (q - x), accumulate sum (q-x)^2.
__global__ void gather_loss(const float* __restrict__ X, const float* __restrict__ Wt,
                            const int* __restrict__ idx, float* __restrict__ out,
                            double* __restrict__ acc) {
    int tid = threadIdx.x;
    float lsum = 0.f;
    #pragma unroll
    for (int i = 0; i < 2; ++i) {
        int flat = i * 256 + tid;
        int rl = flat >> 6;
        int dpos = (flat & 63) * 4;
        size_t row = (size_t)blockIdx.x * 8 + rl;
        int k = idx[row];
        int v = (int)(row >> 13);
        float4 q = *(const float4*)(Wt + ((size_t)v * NK + k) * ND + dpos);
        float4 x = *(const float4*)(X + row * ND + dpos);
        float dx0 = q.x - x.x, dx1 = q.y - x.y, dx2 = q.z - x.z, dx3 = q.w - x.w;
        float4 o;
        o.x = x.x + dx0; o.y = x.y + dx1; o.z = x.z + dx2; o.w = x.w + dx3;
        *(float4*)(out + row * ND + dpos) = o;
        lsum += dx0 * dx0 + dx1 * dx1 + dx2 * dx2 + dx3 * dx3;
    }
    #pragma unroll
    for (int m = 32; m >= 1; m >>= 1) lsum += __shfl_down(lsum, m, 64);
    __shared__ float ws4[4];
    if ((tid & 63) == 0) ws4[tid >> 6] = lsum;
    __syncthreads();
    if (tid == 0) {
        float tot = ws4[0] + ws4[1] + ws4[2] + ws4[3];
        atomicAdd(acc, (double)tot);
    }
}

__global__ void finalize_loss(const double* __restrict__ acc, float* __restrict__ outLoss) {
    *outLoss = (float)(1.25 * (*acc) / (double)((size_t)NV * NN * ND));
}

// ===========================================================================
extern "C" void kernel_launch(void* const* d_in, const int* in_sizes, int n_in,
                              void* d_out, int out_size, void* d_ws, size_t ws_size,
                              hipStream_t stream) {
    const float* X = (const float*)d_in[0];   // [16, 8192, 256]
    const float* W = (const float*)d_in[1];   // [16, 256, 1024]
    float* out = (float*)d_out;               // [16,8192,256] + loss scalar
    char* ws = (char*)d_ws;

    // Workspace layout (Xl contiguous after Xh; Wlt contiguous after Wht)
    const size_t oXh = 0;
    const size_t oXl = oXh + 67108864;
    const size_t oWht = oXl + 67108864;       // 134217728
    const size_t oWlt = oWht + 8388608;       // 142606336
    const size_t oWt = oWlt + 8388608;        // 150994944
    const size_t oWsqd = oWt + 16777216;      // 167772160
    const size_t oWsqf = oWsqd + 131072;      // 167903232
    const size_t oIdx = oWsqf + 65536;        // 167968768
    const size_t oMarg = oIdx + 524288;       // 168493056
    const size_t oList = oMarg + 524288;      // 169017344
    const size_t oAcc = oList + 524288;       // 169541632
    const size_t oCount = oAcc + 8;

    ushort* Xh = (ushort*)(ws + oXh);
    ushort* Xl = (ushort*)(ws + oXl);
    ushort* Wht = (ushort*)(ws + oWht);
    ushort* Wlt = (ushort*)(ws + oWlt);
    float* Wt = (float*)(ws + oWt);
    double* wsqd = (double*)(ws + oWsqd);
    float* wsqf = (float*)(ws + oWsqf);
    int* idx = (int*)(ws + oIdx);
    float* marg = (float*)(ws + oMarg);
    int* list = (int*)(ws + oList);
    double* acc = (double*)(ws + oAcc);
    int* count = (int*)(ws + oCount);

    prep_w<<<dim3(NK / 32, ND / 32, NV), dim3(32, 8), 0, stream>>>(W, Wt, Wht, Wlt);
    wsq_from_wt<<<NV * NK / 4, 256, 0, stream>>>(Wt, wsqd, wsqf, acc, count);
    prep_x<<<2048, 256, 0, stream>>>(X, Xh, Xl);
    score_mfma<<<(NV * NN) / 256, 512, 0, stream>>>(Xh, Wht, wsqf, idx, marg);
    compact<<<(NV * NN) / 256, 256, 0, stream>>>(marg, list, count);
    rescore<<<256, 256, 0, stream>>>(X, W, wsqd, list, count, idx);
    gather_loss<<<(NV * NN) / 8, 256, 0, stream>>>(X, Wt, idx, out, acc);
    finalize_loss<<<1, 1, 0, stream>>>(acc, out + (size_t)NV * NN * ND);
}

// Round 3
// 558.637 us; speedup vs baseline: 1.2863x; 1.2620x over previous
//
#include <hip/hip_runtime.h>

// Problem constants (VectorQuantizer: inputs [V,N,D] fp32, embeddings [V,D,K] fp32)
#define NV 16
#define NN 8192
#define ND 256
#define NK 1024

typedef __attribute__((ext_vector_type(8))) short short8;
typedef __attribute__((ext_vector_type(4))) float f32x4;

// bf16 helpers (RNE)
__device__ __forceinline__ ushort f2bf(float f) {
    uint32_t u = __float_as_uint(f);
    uint32_t r = (u + 0x7FFFu + ((u >> 16) & 1u)) >> 16;
    return (ushort)r;
}
__device__ __forceinline__ float bf2f(ushort h) {
    return __uint_as_float(((uint32_t)h) << 16);
}

// ---------------------------------------------------------------------------
// Transpose W [V,D,K] -> Wt [V,K,D] fp32 (for gather/wsq) + bf16 limb copies.
// Wlt MUST sit exactly 4194304 ushorts after Wht (score kernel assumes it).
// ---------------------------------------------------------------------------
__global__ void prep_w(const float* __restrict__ W, float* __restrict__ Wt,
                       ushort* __restrict__ Wht, ushort* __restrict__ Wlt) {
    __shared__ float tile[32][33];
    int v = blockIdx.z;
    int k0 = blockIdx.x * 32, d0 = blockIdx.y * 32;
    int tx = threadIdx.x, ty = threadIdx.y;         // block (32,8)
    const float* Wv = W + (size_t)v * ND * NK;
    #pragma unroll
    for (int i = 0; i < 4; ++i)
        tile[ty + 8 * i][tx] = Wv[(size_t)(d0 + ty + 8 * i) * NK + k0 + tx];
    __syncthreads();
    size_t ob = (size_t)v * NK * ND;
    #pragma unroll
    for (int i = 0; i < 4; ++i) {
        float val = tile[tx][ty + 8 * i];
        size_t o = ob + (size_t)(k0 + ty + 8 * i) * ND + d0 + tx;
        Wt[o] = val;
        ushort h = f2bf(val);
        Wht[o] = h;
        Wlt[o] = f2bf(val - bf2f(h));
    }
}

// ---------------------------------------------------------------------------
// wsq from transposed Wt (coalesced): one wave per (v,k) row; double reduce.
// Also zeroes the rescore count accumulator.
// ---------------------------------------------------------------------------
__global__ void wsq_from_wt(const float* __restrict__ Wt, double* __restrict__ wsqd,
                            float* __restrict__ wsqf, int* __restrict__ count) {
    int row = blockIdx.x * 4 + (threadIdx.x >> 6);  // V*K rows, 4 waves/block
    int lane = threadIdx.x & 63;
    float4 wv = *(const float4*)(Wt + (size_t)row * ND + lane * 4);
    double s = (double)wv.x * wv.x + (double)wv.y * wv.y +
               (double)wv.z * wv.z + (double)wv.w * wv.w;
    #pragma unroll
    for (int m = 32; m >= 1; m >>= 1) s += __shfl_down(s, m, 64);
    if (lane == 0) { wsqd[row] = s; wsqf[row] = (float)s; }
    if (row == 0 && lane == 0) { *count = 0; }
}

// ---------------------------------------------------------------------------
// X [V,N,D] fp32 -> Xh, Xl bf16 limb arrays (Xl = Xh + 33554432 ushorts).
// ---------------------------------------------------------------------------
__global__ void prep_x(const float* __restrict__ X, ushort* __restrict__ Xh,
                       ushort* __restrict__ Xl) {
    const int nth = gridDim.x * 256;
    for (size_t g = (size_t)blockIdx.x * 256 + threadIdx.x; g < (size_t)NV * NN * ND / 4;
         g += nth) {
        float4 x = *(const float4*)(X + g * 4);
        ushort4 h, l;
        h.x = f2bf(x.x); l.x = f2bf(x.x - bf2f(h.x));
        h.y = f2bf(x.y); l.y = f2bf(x.y - bf2f(h.y));
        h.z = f2bf(x.z); l.z = f2bf(x.z - bf2f(h.z));
        h.w = f2bf(x.w); l.w = f2bf(x.w - bf2f(h.w));
        *(ushort4*)(Xh + g * 4) = h;
        *(ushort4*)(Xl + g * 4) = l;
    }
}

// ---------------------------------------------------------------------------
// MFMA score kernel v5: barrier-minimal double-buffered pipeline.
//   ONE __syncthreads per K-step (drains own staging vmcnt for the buffer
//   about to be read - issued a full step earlier - and licenses overwriting
//   the other buffer). No intra-step barriers/waitcnt; B-fragment reads
//   software-pipelined one phase ahead; 2 waves/SIMD desync to overlap LDS
//   reads with MFMAs (m114 mechanism).
//   256 rows x 256 cols per block, 512 threads (8 waves = 4 row x 2 col),
//   2 x 64KB LDS buffers, XOR-swizzled quads, pre-swizzled global source +
//   linear global_load_lds dest. 2-limb bf16: dot = Xh.Wh + Xh.Wl + Xl.Wh.
//   Tracks best + second-best. XCD-aware block->v mapping.
// ---------------------------------------------------------------------------
#define GLOAD16(SRC, DST)                                                     \
    __builtin_amdgcn_global_load_lds(                                         \
        (const __attribute__((address_space(1))) void*)(SRC),                 \
        (__attribute__((address_space(3))) void*)(DST), 16, 0, 0)

__global__ __launch_bounds__(512, 2) void score_mfma(
    const ushort* __restrict__ Xh, const ushort* __restrict__ Wht,
    const float* __restrict__ wsqf, int* __restrict__ idx, float* __restrict__ marg) {
    // Per buffer (64KB): A [0,32768): limb stride 16384B, slot u16-quad = r*4 + (q ^ ((r>>1)&3))
    //                    B [32768,65536): limb stride 16384B, slot = c*4 + (q ^ ((c>>1)&3))
    // Buffer 1 at +65536.
    __shared__ __align__(16) unsigned char smem[131072];

    const int tid = threadIdx.x;
    const int w = tid >> 6;
    const int l15 = tid & 15;
    const int l4 = (tid >> 4) & 3;
    const int wr = w & 3;                            // row group (64 rows each)
    const int wc = w >> 2;                           // col group (128 cols each)
    const int b = blockIdx.x;
    const int v = (b & 7) * 2 + ((b >> 3) & 1);      // XCD swizzle: 2 codebooks/XCD
    const int n0 = (b >> 4) * 256;

    const ushort* Abase = Xh + (size_t)(v * NN + n0) * ND;     // lo limb at +33554432
    const ushort* Bbase = Wht + (size_t)v * NK * ND;           // lo limb at +4194304

    // staging source offsets (u16 units), constant per thread; A and B share
    // the same (limb, row/col, quad) decomposition: 2048 segs of 16B each.
    unsigned aoff[4], boff[4];
    #pragma unroll
    for (int i = 0; i < 4; ++i) {
        int seg = i * 512 + tid;
        int L = seg >> 10, r = (seg >> 2) & 255, qs = seg & 3;
        int q = qs ^ ((r >> 1) & 3);                 // swizzle: slot qs holds quad q
        aoff[i] = (unsigned)L * 33554432u + (unsigned)r * 256u + (unsigned)q * 8u;
        boff[i] = (unsigned)L * 4194304u + (unsigned)r * 256u + (unsigned)q * 8u;
    }
    // fragment read offsets (bytes within a buffer), constant per thread
    unsigned aro[4], bco[8];
    #pragma unroll
    for (int rt = 0; rt < 4; ++rt) {
        int row = wr * 64 + rt * 16 + l15;
        aro[rt] = (unsigned)(row * 4 + (l4 ^ ((row >> 1) & 3))) * 16u;
    }
    #pragma unroll
    for (int ct = 0; ct < 8; ++ct) {
        int col = wc * 128 + ct * 16 + l15;
        bco[ct] = 32768u + (unsigned)(col * 4 + (l4 ^ ((col >> 1) & 3))) * 16u;
    }

    float m1[16], m2[16];
    int c1[16];
    #pragma unroll
    for (int s = 0; s < 16; ++s) { m1[s] = 3.0e38f; m2[s] = 3.0e38f; c1[s] = 0; }

    f32x4 acc[4][8];
    #pragma unroll
    for (int i = 0; i < 4; ++i)
        #pragma unroll
        for (int j = 0; j < 8; ++j) acc[i][j] = (f32x4){0.f, 0.f, 0.f, 0.f};

    // prologue: stage step 0 into buffer 0 (drained by first __syncthreads)
    #pragma unroll
    for (int i = 0; i < 4; ++i)
        GLOAD16(Abase + aoff[i], smem + (unsigned)(i * 512 + tid) * 16u);
    #pragma unroll
    for (int i = 0; i < 4; ++i)
        GLOAD16(Bbase + boff[i], smem + 32768u + (unsigned)(i * 512 + tid) * 16u);

    // 32 K-steps: cc (256-col chunk) x dc (32-d slice)
    #pragma unroll 1
    for (int cc = 0; cc < 4; ++cc) {
        #pragma unroll 1
        for (int dc = 0; dc < 8; ++dc) {
            const int t = cc * 8 + dc;
            const unsigned pb = (t & 1) ? 65536u : 0u;   // compute buffer
            const unsigned nb = pb ^ 65536u;             // staging buffer

            // ONE barrier per step: drains own staging vmcnt (buffer pb now
            // valid) + all waves done reading nb last step (safe to overwrite)
            __syncthreads();

            if (t < 31) {                            // issue next-step stage ASAP
                const int tn = t + 1;
                const unsigned d0n = (unsigned)(tn & 7) * 32u;
                const unsigned ccn = (unsigned)(tn >> 3) * 65536u;
                #pragma unroll
                for (int i = 0; i < 4; ++i)
                    GLOAD16(Abase + aoff[i] + d0n,
                            smem + nb + (unsigned)(i * 512 + tid) * 16u);
                #pragma unroll
                for (int i = 0; i < 4; ++i)
                    GLOAD16(Bbase + ccn + boff[i] + d0n,
                            smem + nb + 32768u + (unsigned)(i * 512 + tid) * 16u);
            }

            // A fragments for the step
            short8 Ah[4], Al[4];
            #pragma unroll
            for (int rt = 0; rt < 4; ++rt) {
                Ah[rt] = *(const short8*)(smem + pb + aro[rt]);
                Al[rt] = *(const short8*)(smem + pb + aro[rt] + 16384u);
            }
            // B fragments: software-pipelined one phase ahead ([ph&1] slots,
            // ph is compile-time under unroll -> static indexing)
            short8 Bh[2][2], Bl[2][2];
            Bh[0][0] = *(const short8*)(smem + pb + bco[0]);
            Bl[0][0] = *(const short8*)(smem + pb + bco[0] + 16384u);
            Bh[0][1] = *(const short8*)(smem + pb + bco[1]);
            Bl[0][1] = *(const short8*)(smem + pb + bco[1] + 16384u);
            #pragma unroll
            for (int ph = 0; ph < 4; ++ph) {
                const int cur = ph & 1, nxt = cur ^ 1;
                if (ph < 3) {                        // prefetch next phase's B
                    Bh[nxt][0] = *(const short8*)(smem + pb + bco[2 * ph + 2]);
                    Bl[nxt][0] = *(const short8*)(smem + pb + bco[2 * ph + 2] + 16384u);
                    Bh[nxt][1] = *(const short8*)(smem + pb + bco[2 * ph + 3]);
                    Bl[nxt][1] = *(const short8*)(smem + pb + bco[2 * ph + 3] + 16384u);
                }
                __builtin_amdgcn_s_setprio(1);
                #pragma unroll
                for (int rt = 0; rt < 4; ++rt) {
                    f32x4 a0 = acc[rt][2 * ph];
                    a0 = __builtin_amdgcn_mfma_f32_16x16x32_bf16(Ah[rt], Bh[cur][0], a0, 0, 0, 0);
                    a0 = __builtin_amdgcn_mfma_f32_16x16x32_bf16(Ah[rt], Bl[cur][0], a0, 0, 0, 0);
                    a0 = __builtin_amdgcn_mfma_f32_16x16x32_bf16(Al[rt], Bh[cur][0], a0, 0, 0, 0);
                    acc[rt][2 * ph] = a0;
                    f32x4 a1 = acc[rt][2 * ph + 1];
                    a1 = __builtin_amdgcn_mfma_f32_16x16x32_bf16(Ah[rt], Bh[cur][1], a1, 0, 0, 0);
                    a1 = __builtin_amdgcn_mfma_f32_16x16x32_bf16(Ah[rt], Bl[cur][1], a1, 0, 0, 0);
                    a1 = __builtin_amdgcn_mfma_f32_16x16x32_bf16(Al[rt], Bh[cur][1], a1, 0, 0, 0);
                    acc[rt][2 * ph + 1] = a1;
                }
                __builtin_amdgcn_s_setprio(0);
            }
        }
        // fold chunk scores into running best/second (lane stream ascending c)
        #pragma unroll
        for (int ct = 0; ct < 8; ++ct) {
            int c = cc * 256 + wc * 128 + ct * 16 + l15;
            float wf = wsqf[v * NK + c];
            #pragma unroll
            for (int rt = 0; rt < 4; ++rt)
                #pragma unroll
                for (int reg = 0; reg < 4; ++reg) {
                    int slot = rt * 4 + reg;
                    float s = fmaf(-2.0f, acc[rt][ct][reg], wf);
                    bool better = s < m1[slot];
                    m2[slot] = better ? m1[slot] : fminf(m2[slot], s);
                    c1[slot] = better ? c : c1[slot];
                    m1[slot] = better ? s : m1[slot];
                }
        }
        #pragma unroll
        for (int i = 0; i < 4; ++i)
            #pragma unroll
            for (int j = 0; j < 8; ++j) acc[i][j] = (f32x4){0.f, 0.f, 0.f, 0.f};
    }
    __syncthreads();

    // merge across the 16 lanes sharing each row (C layout: col = lane&15)
    float* mS = (float*)smem;                        // [2][256]
    int* mC = (int*)(smem + 2048);
    float* mS2 = (float*)(smem + 4096);
    #pragma unroll
    for (int rt = 0; rt < 4; ++rt)
        #pragma unroll
        for (int reg = 0; reg < 4; ++reg) {
            int slot = rt * 4 + reg;
            float s1 = m1[slot], s2v = m2[slot];
            int c = c1[slot];
            #pragma unroll
            for (int m = 1; m < 16; m <<= 1) {
                float s1o = __shfl_xor(s1, m, 64);
                float s2o = __shfl_xor(s2v, m, 64);
                int co = __shfl_xor(c, m, 64);
                bool take = (s1o < s1) || (s1o == s1 && co < c);  // tie -> smaller c
                float big = take ? s1 : s1o;
                s2v = fminf(fminf(s2v, s2o), big);
                s1 = take ? s1o : s1;
                c = take ? co : c;
            }
            if (l15 == 0) {
                int rowl = wr * 64 + rt * 16 + l4 * 4 + reg;  // C row = quad*4+reg
                mS[wc * 256 + rowl] = s1;
                mC[wc * 256 + rowl] = c;
                mS2[wc * 256 + rowl] = s2v;
            }
        }
    __syncthreads();
    if (tid < 256) {                                  // merge the two col-halves
        float s1a = mS[tid], s1b = mS[256 + tid];
        int ca = mC[tid], cb = mC[256 + tid];
        float s2a = mS2[tid], s2b = mS2[256 + tid];
        bool take = (s1b < s1a) || (s1b == s1a && cb < ca);
        float s1 = take ? s1b : s1a;
        int c = take ? cb : ca;
        float s2v = fminf(fminf(s2a, s2b), take ? s1a : s1b);
        idx[v * NN + n0 + tid] = c;
        marg[v * NN + n0 + tid] = s2v - s1;
    }
}
#undef GLOAD16

// Rows with small margin -> compacted list for exact rescoring.
__global__ void compact(const float* __restrict__ marg, int* __restrict__ list,
                        int* __restrict__ count) {
    int r = blockIdx.x * 256 + threadIdx.x;
    if (marg[r] < 0.04f) {
        int p = atomicAdd(count, 1);
        list[p] = r;
    }
}

// Exact fp32 rescore (sequential fmaf over d, double compare, tie -> smaller c)
__global__ __launch_bounds__(256) void rescore(
    const float* __restrict__ X, const float* __restrict__ W,
    const double* __restrict__ wsqd, const int* __restrict__ list,
    const int* __restrict__ count, int* __restrict__ idx) {
    __shared__ float xs[256];
    __shared__ double rs[4];
    __shared__ int rc[4];
    int tid = threadIdx.x;
    int nrows = *count;
    for (int j = blockIdx.x; j < nrows; j += gridDim.x) {
        int row = list[j];
        int v = row >> 13;
        __syncthreads();
        xs[tid] = X[(size_t)row * ND + tid];
        __syncthreads();
        const float* Wv = W + (size_t)v * ND * NK;
        float p0 = 0.f, p1 = 0.f, p2 = 0.f, p3 = 0.f;
        int cb = tid * 4;
        for (int d = 0; d < ND; ++d) {
            float xd = xs[d];
            float4 wv = *(const float4*)(Wv + (size_t)d * NK + cb);
            p0 = fmaf(xd, wv.x, p0);
            p1 = fmaf(xd, wv.y, p1);
            p2 = fmaf(xd, wv.z, p2);
            p3 = fmaf(xd, wv.w, p3);
        }
        const double* wv2 = wsqd + v * NK;
        double s0 = wv2[cb] - 2.0 * (double)p0;
        double s1 = wv2[cb + 1] - 2.0 * (double)p1;
        double s2 = wv2[cb + 2] - 2.0 * (double)p2;
        double s3 = wv2[cb + 3] - 2.0 * (double)p3;
        double bsv = s0;
        int bcv = cb;
        if (s1 < bsv) { bsv = s1; bcv = cb + 1; }
        if (s2 < bsv) { bsv = s2; bcv = cb + 2; }
        if (s3 < bsv) { bsv = s3; bcv = cb + 3; }
        for (int m = 1; m < 64; m <<= 1) {
            double so = __shfl_xor(bsv, m, 64);
            int co = __shfl_xor(bcv, m, 64);
            if (so < bsv || (so == bsv && co < bcv)) { bsv = so; bcv = co; }
        }
        if ((tid & 63) == 0) { rs[tid >> 6] = bsv; rc[tid >> 6] = bcv; }
        __syncthreads();
        if (tid == 0) {
            double bq = rs[0];
            int c = rc[0];
            for (int i2 = 1; i2 < 4; ++i2)
                if (rs[i2] < bq || (rs[i2] == bq && rc[i2] < c)) { bq = rs[i2]; c = rc[i2]; }
            idx[row] = c;
        }
        __syncthreads();
    }
}

// ---------------------------------------------------------------------------
// Gather v2: 2048 blocks x 64 rows. Diagnosis of v1 (206us at 13.6% HBM,
// VALUBusy 4%): 16384 same-address atomicAdd(double) serialize at the
// coherence point (~10ns each ~= the 150us gap over the BW bound), plus a
// 2-deep dependent idx->gather chain and no XCD locality for the Wt gather.
// Fix: (a) one partial double per block into a scratch array (no atomics),
// reduced by finalize_loss; (b) preload all 16 idx values per thread up
// front (independent loads in flight); (c) XCD-aware block->v mapping so
// each XCD gathers from 2 codebooks (2MB, L2-resident).
// Per-element math unchanged: out = x + (q - x), fp32.
// ---------------------------------------------------------------------------
__global__ __launch_bounds__(256) void gather_loss(
    const float* __restrict__ X, const float* __restrict__ Wt,
    const int* __restrict__ idx, float* __restrict__ out,
    double* __restrict__ partial) {
    const int b = blockIdx.x;
    const int v = (b & 7) * 2 + ((b >> 3) & 1);      // XCD swizzle: 2 codebooks/XCD
    const int r0 = (b >> 4) * 64;                    // row base within v (128 chunks)
    const int tid = threadIdx.x;
    const int g = tid >> 6;                          // row group 0..3
    const int lane = tid & 63;
    const int dpos = lane * 4;
    const float* Wv = Wt + (size_t)v * NK * ND;
    const size_t rowbase = (size_t)v * NN + r0;
    const int* idxv = idx + rowbase;

    int kv[16];
    #pragma unroll
    for (int i = 0; i < 16; ++i) kv[i] = idxv[i * 4 + g];

    double dsum = 0.0;
    #pragma unroll 4
    for (int i = 0; i < 16; ++i) {
        size_t row = rowbase + (size_t)(i * 4 + g);
        float4 q = *(const float4*)(Wv + (size_t)kv[i] * ND + dpos);
        float4 x = *(const float4*)(X + row * ND + dpos);
        float dx0 = q.x - x.x, dx1 = q.y - x.y, dx2 = q.z - x.z, dx3 = q.w - x.w;
        float4 o;
        o.x = x.x + dx0; o.y = x.y + dx1; o.z = x.z + dx2; o.w = x.w + dx3;
        *(float4*)(out + row * ND + dpos) = o;
        dsum += (double)(dx0 * dx0 + dx1 * dx1 + dx2 * dx2 + dx3 * dx3);
    }
    #pragma unroll
    for (int m = 32; m >= 1; m >>= 1) dsum += __shfl_down(dsum, m, 64);
    __shared__ double ws4[4];
    if (lane == 0) ws4[g] = dsum;
    __syncthreads();
    if (tid == 0) partial[b] = ws4[0] + ws4[1] + ws4[2] + ws4[3];
}

__global__ __launch_bounds__(256) void finalize_loss(const double* __restrict__ partial,
                                                     float* __restrict__ outLoss) {
    int tid = threadIdx.x;
    double s = 0.0;
    #pragma unroll
    for (int i = 0; i < 8; ++i) s += partial[tid + i * 256];
    #pragma unroll
    for (int m = 32; m >= 1; m >>= 1) s += __shfl_down(s, m, 64);
    __shared__ double sw[4];
    if ((tid & 63) == 0) sw[tid >> 6] = s;
    __syncthreads();
    if (tid == 0) {
        double tot = sw[0] + sw[1] + sw[2] + sw[3];
        *outLoss = (float)(1.25 * tot / (double)((size_t)NV * NN * ND));
    }
}

// ===========================================================================
extern "C" void kernel_launch(void* const* d_in, const int* in_sizes, int n_in,
                              void* d_out, int out_size, void* d_ws, size_t ws_size,
                              hipStream_t stream) {
    const float* X = (const float*)d_in[0];   // [16, 8192, 256]
    const float* W = (const float*)d_in[1];   // [16, 256, 1024]
    float* out = (float*)d_out;               // [16,8192,256] + loss scalar
    char* ws = (char*)d_ws;

    // Workspace layout (Xl contiguous after Xh; Wlt contiguous after Wht)
    const size_t oXh = 0;
    const size_t oXl = oXh + 67108864;
    const size_t oWht = oXl + 67108864;       // 134217728
    const size_t oWlt = oWht + 8388608;       // 142606336
    const size_t oWt = oWlt + 8388608;        // 150994944
    const size_t oWsqd = oWt + 16777216;      // 167772160
    const size_t oWsqf = oWsqd + 131072;      // 167903232
    const size_t oIdx = oWsqf + 65536;        // 167968768
    const size_t oMarg = oIdx + 524288;       // 168493056
    const size_t oList = oMarg + 524288;      // 169017344
    const size_t oCount = oList + 524288;     // 169541632

    ushort* Xh = (ushort*)(ws + oXh);
    ushort* Xl = (ushort*)(ws + oXl);
    ushort* Wht = (ushort*)(ws + oWht);
    ushort* Wlt = (ushort*)(ws + oWlt);
    float* Wt = (float*)(ws + oWt);
    double* wsqd = (double*)(ws + oWsqd);
    float* wsqf = (float*)(ws + oWsqf);
    int* idx = (int*)(ws + oIdx);
    float* marg = (float*)(ws + oMarg);
    int* list = (int*)(ws + oList);
    int* count = (int*)(ws + oCount);
    // partial sums reuse the marg region (dead after compact); 2048 doubles
    double* partial = (double*)(ws + oMarg);

    prep_w<<<dim3(NK / 32, ND / 32, NV), dim3(32, 8), 0, stream>>>(W, Wt, Wht, Wlt);
    wsq_from_wt<<<NV * NK / 4, 256, 0, stream>>>(Wt, wsqd, wsqf, count);
    prep_x<<<2048, 256, 0, stream>>>(X, Xh, Xl);
    score_mfma<<<(NV * NN) / 256, 512, 0, stream>>>(Xh, Wht, wsqf, idx, marg);
    compact<<<(NV * NN) / 256, 256, 0, stream>>>(marg, list, count);
    rescore<<<256, 256, 0, stream>>>(X, W, wsqd, list, count, idx);
    gather_loss<<<2048, 256, 0, stream>>>(X, Wt, idx, out, partial);
    finalize_loss<<<1, 256, 0, stream>>>(partial, out + (size_t)NV * NN * ND);
}